// Round 12
// baseline (660.661 us; speedup 1.0000x reference)
//
#include <hip/hip_runtime.h>
#include <math.h>

#define NN 50000
#define RR 8
#define EE 800000
#define RN 400000            // RR * NN
#define DIN 128
#define K1 1024              // RR * DIN
#define KTOT 1152            // K1 + DIN
#define NBLK 391             // ceil(RN / 1024)
#define LDW 1160             // LDS row width (elems) = 145 16B-chunks (ODD -> natural
                             // per-row bank rotation; NO XOR swizzle — R10 post-mortem)

// ---------------- workspace layout (bytes) ----------------
#define OFF_HB0  0UL           // h bf16: [NN][128] = 12,800,000
#define OFF_HB1  12800000UL    // h bf16: [NN][128] = 12,800,000
#define OFF_XB   25600000UL    // x bf16: [NN][128] = 12,800,000
#define OFF_LG   38400000UL    // logits f32: [NN][64] = 12,800,000
#define OFF_WT   51200000UL    // W^T bf16: 4 x 147456 elems = 1,179,648
#define OFF_OFFS 52379648UL    // offsets: (RN+1) ints -> 1,600,128
#define OFF_CUR  53979776UL    // cursor/hist: RN ints = 1,600,000
#define OFF_SRT  55579776UL    // sorted_src: EE ints = 3,200,000
#define OFF_BS   58779776UL    // block sums = 4,096
#define WS_NEED  58783872UL

typedef short bf16x8 __attribute__((ext_vector_type(8)));
typedef float f32x4 __attribute__((ext_vector_type(4)));

__device__ __forceinline__ unsigned f2bf(float f) {       // RNE f32 -> bf16 bits
    unsigned x = __float_as_uint(f);
    return (x + 0x7fffu + ((x >> 16) & 1u)) >> 16;
}
__device__ __forceinline__ float bflo(unsigned p) { return __uint_as_float(p << 16); }
__device__ __forceinline__ float bfhi(unsigned p) { return __uint_as_float(p & 0xffff0000u); }

// ---------------- one-time converts ----------------
__global__ void k_cvt(const float* __restrict__ x, ushort* __restrict__ xb) {
    int i = blockIdx.x * 256 + threadIdx.x;
    if (i >= NN * 32) return;                 // float4 granules
    float4 v = ((const float4*)x)[i];
    ushort4 o;
    o.x = (ushort)f2bf(v.x); o.y = (ushort)f2bf(v.y);
    o.z = (ushort)f2bf(v.z); o.w = (ushort)f2bf(v.w);
    ((ushort4*)xb)[i] = o;
}

// build W^T[o][k] bf16, k in [0,1152): k<1024 -> W[k>>7][k&127][o], else root[k-1024][o]
__global__ void k_wt(const float* __restrict__ W, const float* __restrict__ Rt,
                     ushort* __restrict__ WT, int O) {
    int o = blockIdx.x;
    for (int k = threadIdx.x; k < KTOT; k += 256) {
        float v = (k < K1)
            ? W[(size_t)(k >> 7) * 128 * O + (size_t)(k & 127) * O + o]
            : Rt[(size_t)(k - K1) * O + o];
        WT[(size_t)o * KTOT + k] = (ushort)f2bf(v);
    }
}

// ---------------- edge preprocessing (counting sort by s = dst*8 + r) ----------------
__global__ void k_hist(const int* __restrict__ ei, const int* __restrict__ et,
                       int* __restrict__ hist) {
    int e = blockIdx.x * blockDim.x + threadIdx.x;
    if (e >= EE) return;
    atomicAdd(&hist[ei[EE + e] * RR + et[e]], 1);
}

__global__ void k_scan1(const int* __restrict__ hist, int* __restrict__ offs,
                        int* __restrict__ bsums) {
    __shared__ int tmp[1024];
    int tid = threadIdx.x;
    int g = blockIdx.x * 1024 + tid;
    int v = (g < RN) ? hist[g] : 0;
    tmp[tid] = v;
    __syncthreads();
    for (int off = 1; off < 1024; off <<= 1) {
        int t = tmp[tid];
        if (tid >= off) t += tmp[tid - off];
        __syncthreads();
        tmp[tid] = t;
        __syncthreads();
    }
    if (g < RN) offs[g] = tmp[tid] - v;
    if (tid == 1023) bsums[blockIdx.x] = tmp[1023];
}

__global__ void k_scan2(int* __restrict__ bsums) {
    __shared__ int tmp[1024];
    int tid = threadIdx.x;
    int v = (tid < NBLK) ? bsums[tid] : 0;
    tmp[tid] = v;
    __syncthreads();
    for (int off = 1; off < 1024; off <<= 1) {
        int t = tmp[tid];
        if (tid >= off) t += tmp[tid - off];
        __syncthreads();
        tmp[tid] = t;
        __syncthreads();
    }
    if (tid < NBLK) bsums[tid] = tmp[tid] - v;
}

__global__ void k_scan3(int* __restrict__ offs, const int* __restrict__ bsums) {
    int g = blockIdx.x * 1024 + threadIdx.x;
    if (g < RN) offs[g] += bsums[blockIdx.x];
    else if (g == RN) offs[RN] = EE;
}

__global__ void k_scatter(const int* __restrict__ ei, const int* __restrict__ et,
                          const int* __restrict__ offs, int* __restrict__ cur,
                          int* __restrict__ ssrc) {
    int e = blockIdx.x * blockDim.x + threadIdx.x;
    if (e >= EE) return;
    int s = ei[EE + e] * RR + et[e];
    ssrc[offs[s] + atomicAdd(&cur[s], 1)] = ei[e];
}

// ---------------- fused layer: agg -> LDS -> MFMA, one barrier ----------------
// Block = 32 nodes, 1024 threads (16 waves); 1563 blocks; 74KB LDS -> 2
// blocks/CU -> 32 waves/CU (FULL occupancy; R11 post-mortem: 8-wave blocks
// left all pipes idle at 16 waves/CU — gather is L2-latency bound, waves are
// the lever). Phase 1: wave w aggregates nodes 2w,2w+1; per node quarter-wave
// (16 lanes x uint4 = full 256B row) per relation, 4 relations concurrent x 2
// passes, 2-deep edge unroll. shfl-safety: all shfls full-exec (uniform trip
// = max over quarters, clamped indices); validity guards VALU only. Phase 2:
// 16 waves <-> (col-tile, m-subtile) tasks; 36 MFMA each vs L2-resident WT.
template<int O, bool RELU, bool OUTF32>
__global__ __launch_bounds__(1024, 8) void k_fused(
        const ushort* __restrict__ hb, const int* __restrict__ offs,
        const int* __restrict__ ssrc, const ushort* __restrict__ WT,
        const float* __restrict__ bias, void* __restrict__ outv) {
    __shared__ ushort As[32 * LDW];
    const int tid = threadIdx.x;
    const int lane = tid & 63;
    const int w = tid >> 6;                  // 0..15
    const int q = lane >> 4;                 // quarter 0..3 = relation slot
    const int ll = lane & 15;                // 16B chunk within row
    const int nbase = blockIdx.x * 32;
    const uint4* h16 = (const uint4*)hb;     // h row = 16 uint4

    // ---- phase 1: gather/aggregate 2 nodes per wave
    for (int i = 0; i < 2; ++i) {            // wave-uniform
        int nl = w * 2 + i;
        int n = min(nbase + nl, NN - 1);     // clamp tail (junk rows masked later)
        int b = offs[n * 8 + min(lane, 8)];
        int b0 = __shfl(b, 0), b8 = __shfl(b, 8);
        int nb = b8 - b0;
        int sv = ssrc[min(b0 + min(lane, max(nb - 1, 0)), EE - 1)];
#pragma unroll
        for (int p = 0; p < 2; ++p) {        // relation pass: r = p*4 + q
            int r = p * 4 + q;
            int beg = __shfl(b, r);          // full exec, per-lane index ok
            int end = __shfl(b, r + 1);
            int len = end - beg;
            int mx = max(max(__shfl(len, 0), __shfl(len, 16)),
                         max(__shfl(len, 32), __shfl(len, 48)));  // wave-uniform
            int begl = beg - b0;
            float a0 = 0.f, a1 = 0.f, a2 = 0.f, a3 = 0.f;
            float a4 = 0.f, a5 = 0.f, a6 = 0.f, a7 = 0.f;
            for (int j = 0; j < mx; j += 2) {   // uniform trip: full exec
                int e0 = begl + j, e1 = e0 + 1;
                int s0 = __shfl(sv, min(e0, 63));
                int s1 = __shfl(sv, min(e1, 63));
                if (e1 >= 64) {                 // rare: node degree > 64
                    s0 = ssrc[min(b0 + e0, EE - 1)];
                    s1 = ssrc[min(b0 + e1, EE - 1)];
                }
                uint4 u0 = h16[(size_t)s0 * 16 + ll];
                uint4 u1 = h16[(size_t)s1 * 16 + ll];
                if (j < len) {
                    a0 += bflo(u0.x); a1 += bfhi(u0.x);
                    a2 += bflo(u0.y); a3 += bfhi(u0.y);
                    a4 += bflo(u0.z); a5 += bfhi(u0.z);
                    a6 += bflo(u0.w); a7 += bfhi(u0.w);
                }
                if (j + 1 < len) {
                    a0 += bflo(u1.x); a1 += bfhi(u1.x);
                    a2 += bflo(u1.y); a3 += bfhi(u1.y);
                    a4 += bflo(u1.z); a5 += bfhi(u1.z);
                    a6 += bflo(u1.w); a7 += bfhi(u1.w);
                }
            }
            float inv = 1.0f / (float)max(len, 1);
            uint4 o;
            o.x = f2bf(a0 * inv) | (f2bf(a1 * inv) << 16);
            o.y = f2bf(a2 * inv) | (f2bf(a3 * inv) << 16);
            o.z = f2bf(a4 * inv) | (f2bf(a5 * inv) << 16);
            o.w = f2bf(a6 * inv) | (f2bf(a7 * inv) << 16);
            *(uint4*)(&As[nl * LDW + (r * 16 + ll) * 8]) = o;
        }
    }
    // ---- root rows: cols [1024,1152) = chunks [128,144); 512 thr x 16B = 32 rows
    if (tid < 512) {
        int row = tid >> 4;                  // 0..31
        int cc = tid & 15;
        uint4 v = h16[(size_t)min(nbase + row, NN - 1) * 16 + cc];
        *(uint4*)(&As[row * LDW + (128 + cc) * 8]) = v;
    }
    __syncthreads();
    // ---- phase 2: 16 waves <-> tasks. O=128: cw=w&7, mt=w>>3 (16 tasks).
    //      O=64: waves 0..7: cw=w&3, mt=w>>2 (8 tasks); waves 8..15 idle.
    constexpr int NW2 = (O == 128) ? 16 : 8;
    if (w < NW2) {
        const int cw = (O == 128) ? (w & 7) : (w & 3);
        const int mt = (O == 128) ? (w >> 3) : (w >> 2);
        const int lr = lane & 15, hi = lane >> 4;
        f32x4 acc = {};
        const ushort* wcol = WT + (size_t)(cw * 16 + lr) * KTOT + hi * 8;
#pragma unroll
        for (int ks = 0; ks < 36; ++ks) {
            bf16x8 bb = *(const bf16x8*)(wcol + ks * 32);
            int g = ks * 4 + hi;
            int row = mt * 16 + lr;
            bf16x8 a = *(const bf16x8*)(&As[row * LDW + g * 8]);
            acc = __builtin_amdgcn_mfma_f32_16x16x32_bf16(a, bb, acc, 0, 0, 0);
        }
        int col = cw * 16 + lr;
        float bs = bias[col];
#pragma unroll
        for (int j = 0; j < 4; ++j) {        // C/D: col=lane&15, row=(lane>>4)*4+j
            int row = nbase + mt * 16 + hi * 4 + j;
            if (row >= NN) continue;
            float v = acc[j] + bs;
            if (RELU) v = fmaxf(v, 0.f);
            if (OUTF32) ((float*)outv)[(size_t)row * O + col] = v;
            else ((ushort*)outv)[(size_t)row * O + col] = (ushort)f2bf(v);
        }
    }
}

// ---------------- final log_softmax over 64 cols ----------------
__global__ void k_logsoftmax(const float* __restrict__ in, float* __restrict__ out) {
    int row = blockIdx.x * 4 + (threadIdx.x >> 6);
    int lane = threadIdx.x & 63;
    if (row >= NN) return;
    float v = in[(size_t)row * 64 + lane];
    float m = v;
#pragma unroll
    for (int off = 32; off; off >>= 1) m = fmaxf(m, __shfl_xor(m, off, 64));
    float e = expf(v - m);
    float s = e;
#pragma unroll
    for (int off = 32; off; off >>= 1) s += __shfl_xor(s, off, 64);
    out[(size_t)row * 64 + lane] = v - m - logf(s);
}

extern "C" void kernel_launch(void* const* d_in, const int* in_sizes, int n_in,
                              void* d_out, int out_size, void* d_ws, size_t ws_size,
                              hipStream_t stream) {
    const float* x  = (const float*)d_in[0];
    const int*   ei = (const int*)d_in[1];
    const int*   et = (const int*)d_in[2];
    const float* W[4]    = {(const float*)d_in[3], (const float*)d_in[6],
                            (const float*)d_in[9], (const float*)d_in[12]};
    const float* root[4] = {(const float*)d_in[4], (const float*)d_in[7],
                            (const float*)d_in[10], (const float*)d_in[13]};
    const float* bias[4] = {(const float*)d_in[5], (const float*)d_in[8],
                            (const float*)d_in[11], (const float*)d_in[14]};

    if (ws_size < WS_NEED) return;

    char* ws = (char*)d_ws;
    ushort* hb0  = (ushort*)(ws + OFF_HB0);
    ushort* hb1  = (ushort*)(ws + OFF_HB1);
    ushort* xb   = (ushort*)(ws + OFF_XB);
    float*  lg   = (float*)(ws + OFF_LG);
    ushort* WT   = (ushort*)(ws + OFF_WT);
    int*   offs  = (int*)(ws + OFF_OFFS);
    int*   cur   = (int*)(ws + OFF_CUR);
    int*   ssrc  = (int*)(ws + OFF_SRT);
    int*   bsums = (int*)(ws + OFF_BS);
    ushort* WTl[4] = {WT, WT + 147456, WT + 2 * 147456, WT + 3 * 147456};

    // one-time converts
    k_cvt<<<(NN * 32 + 255) / 256, 256, 0, stream>>>(x, xb);
    k_wt<<<128, 256, 0, stream>>>(W[0], root[0], WTl[0], 128);
    k_wt<<<128, 256, 0, stream>>>(W[1], root[1], WTl[1], 128);
    k_wt<<<128, 256, 0, stream>>>(W[2], root[2], WTl[2], 128);
    k_wt<<<64,  256, 0, stream>>>(W[3], root[3], WTl[3], 64);

    // edge sort by segment key s = dst*8 + etype
    hipMemsetAsync(cur, 0, RN * sizeof(int), stream);
    k_hist<<<(EE + 255) / 256, 256, 0, stream>>>(ei, et, cur);
    k_scan1<<<NBLK, 1024, 0, stream>>>(cur, offs, bsums);
    k_scan2<<<1, 1024, 0, stream>>>(bsums);
    k_scan3<<<NBLK, 1024, 0, stream>>>(offs, bsums);
    hipMemsetAsync(cur, 0, RN * sizeof(int), stream);
    k_scatter<<<(EE + 255) / 256, 256, 0, stream>>>(ei, et, offs, cur, ssrc);

    const int G = (NN + 31) / 32;   // 1563
    k_fused<128, true,  false><<<G, 1024, 0, stream>>>(xb,  offs, ssrc, WTl[0], bias[0], hb0);
    k_fused<128, true,  false><<<G, 1024, 0, stream>>>(hb0, offs, ssrc, WTl[1], bias[1], hb1);
    k_fused<128, true,  false><<<G, 1024, 0, stream>>>(hb1, offs, ssrc, WTl[2], bias[2], hb0);
    k_fused<64,  false, true ><<<G, 1024, 0, stream>>>(hb0, offs, ssrc, WTl[3], bias[3], lg);
    k_logsoftmax<<<(NN + 3) / 4, 256, 0, stream>>>(lg, (float*)d_out);
}

// Round 13
// 631.698 us; speedup vs baseline: 1.0458x; 1.0458x over previous
//
#include <hip/hip_runtime.h>
#include <math.h>

#define NN 50000
#define RR 8
#define EE 800000
#define RN 400000            // RR * NN
#define DIN 128
#define K1 1024              // RR * DIN
#define KTOT 1152            // K1 + DIN
#define NBLK 391             // ceil(RN / 1024)
#define LDW 1160             // LDS row width (elems) = 145 16B-chunks (ODD -> natural
                             // per-row bank rotation; NO XOR swizzle — R10 post-mortem)

// ---------------- workspace layout (bytes) ----------------
#define OFF_HB0  0UL           // h bf16: [NN][128] = 12,800,000
#define OFF_HB1  12800000UL    // h bf16: [NN][128] = 12,800,000
#define OFF_XB   25600000UL    // x bf16: [NN][128] = 12,800,000
#define OFF_LG   38400000UL    // logits f32: [NN][64] = 12,800,000
#define OFF_WT   51200000UL    // W^T bf16: 4 x 147456 elems = 1,179,648
#define OFF_OFFS 52379648UL    // offsets: (RN+1) ints -> 1,600,128
#define OFF_CUR  53979776UL    // cursor/hist: RN ints = 1,600,000
#define OFF_SRT  55579776UL    // sorted_src: EE ints = 3,200,000
#define OFF_BS   58779776UL    // block sums = 4,096
#define WS_NEED  58783872UL

typedef short bf16x8 __attribute__((ext_vector_type(8)));
typedef float f32x4 __attribute__((ext_vector_type(4)));

__device__ __forceinline__ unsigned f2bf(float f) {       // RNE f32 -> bf16 bits
    unsigned x = __float_as_uint(f);
    return (x + 0x7fffu + ((x >> 16) & 1u)) >> 16;
}
__device__ __forceinline__ float bflo(unsigned p) { return __uint_as_float(p << 16); }
__device__ __forceinline__ float bfhi(unsigned p) { return __uint_as_float(p & 0xffff0000u); }

// ---------------- one-time converts ----------------
__global__ void k_cvt(const float* __restrict__ x, ushort* __restrict__ xb) {
    int i = blockIdx.x * 256 + threadIdx.x;
    if (i >= NN * 32) return;                 // float4 granules
    float4 v = ((const float4*)x)[i];
    ushort4 o;
    o.x = (ushort)f2bf(v.x); o.y = (ushort)f2bf(v.y);
    o.z = (ushort)f2bf(v.z); o.w = (ushort)f2bf(v.w);
    ((ushort4*)xb)[i] = o;
}

// build W^T[o][k] bf16, k in [0,1152): k<1024 -> W[k>>7][k&127][o], else root[k-1024][o]
__global__ void k_wt(const float* __restrict__ W, const float* __restrict__ Rt,
                     ushort* __restrict__ WT, int O) {
    int o = blockIdx.x;
    for (int k = threadIdx.x; k < KTOT; k += 256) {
        float v = (k < K1)
            ? W[(size_t)(k >> 7) * 128 * O + (size_t)(k & 127) * O + o]
            : Rt[(size_t)(k - K1) * O + o];
        WT[(size_t)o * KTOT + k] = (ushort)f2bf(v);
    }
}

// ---------------- edge preprocessing (counting sort by s = dst*8 + r) ----------------
__global__ void k_hist(const int* __restrict__ ei, const int* __restrict__ et,
                       int* __restrict__ hist) {
    int e = blockIdx.x * blockDim.x + threadIdx.x;
    if (e >= EE) return;
    atomicAdd(&hist[ei[EE + e] * RR + et[e]], 1);
}

__global__ void k_scan1(const int* __restrict__ hist, int* __restrict__ offs,
                        int* __restrict__ bsums) {
    __shared__ int tmp[1024];
    int tid = threadIdx.x;
    int g = blockIdx.x * 1024 + tid;
    int v = (g < RN) ? hist[g] : 0;
    tmp[tid] = v;
    __syncthreads();
    for (int off = 1; off < 1024; off <<= 1) {
        int t = tmp[tid];
        if (tid >= off) t += tmp[tid - off];
        __syncthreads();
        tmp[tid] = t;
        __syncthreads();
    }
    if (g < RN) offs[g] = tmp[tid] - v;
    if (tid == 1023) bsums[blockIdx.x] = tmp[1023];
}

__global__ void k_scan2(int* __restrict__ bsums) {
    __shared__ int tmp[1024];
    int tid = threadIdx.x;
    int v = (tid < NBLK) ? bsums[tid] : 0;
    tmp[tid] = v;
    __syncthreads();
    for (int off = 1; off < 1024; off <<= 1) {
        int t = tmp[tid];
        if (tid >= off) t += tmp[tid - off];
        __syncthreads();
        tmp[tid] = t;
        __syncthreads();
    }
    if (tid < NBLK) bsums[tid] = tmp[tid] - v;
}

__global__ void k_scan3(int* __restrict__ offs, const int* __restrict__ bsums) {
    int g = blockIdx.x * 1024 + threadIdx.x;
    if (g < RN) offs[g] += bsums[blockIdx.x];
    else if (g == RN) offs[RN] = EE;
}

__global__ void k_scatter(const int* __restrict__ ei, const int* __restrict__ et,
                          const int* __restrict__ offs, int* __restrict__ cur,
                          int* __restrict__ ssrc) {
    int e = blockIdx.x * blockDim.x + threadIdx.x;
    if (e >= EE) return;
    int s = ei[EE + e] * RR + et[e];
    ssrc[offs[s] + atomicAdd(&cur[s], 1)] = ei[e];
}

// ---------------- fused layer: agg -> LDS -> MFMA, one barrier ----------------
// R11 structure (best: 512 thr / 8 waves, VGPR free-running at ~52 — R12
// showed forcing 32 waves/CU collapses VGPR to 32 and serializes the gather;
// in-flight load depth per lane > wave count for this latency-bound gather).
// R13 change: h-row loads PREDICATED by validity (if j<len) — the uniform
// max-trip loop previously issued ~2x clamped-garbage loads (Poisson(2) len,
// mx=max of 4). All __shfl remain at FULL exec (safety invariant); only
// loads/VALU are masked. Gather traffic halves.
template<int O, bool RELU, bool OUTF32>
__global__ __launch_bounds__(512) void k_fused(
        const ushort* __restrict__ hb, const int* __restrict__ offs,
        const int* __restrict__ ssrc, const ushort* __restrict__ WT,
        const float* __restrict__ bias, void* __restrict__ outv) {
    __shared__ ushort As[32 * LDW];
    const int tid = threadIdx.x;
    const int lane = tid & 63;
    const int w = tid >> 6;                  // 0..7
    const int q = lane >> 4;                 // quarter 0..3 = relation slot
    const int ll = lane & 15;                // 16B chunk within row
    const int nbase = blockIdx.x * 32;
    const uint4* h16 = (const uint4*)hb;     // h row = 16 uint4

    // ---- phase 1: gather/aggregate 4 nodes per wave
    for (int i = 0; i < 4; ++i) {            // wave-uniform
        int nl = w * 4 + i;
        int n = min(nbase + nl, NN - 1);     // clamp tail (junk rows masked later)
        int b = offs[n * 8 + min(lane, 8)];
        int b0 = __shfl(b, 0), b8 = __shfl(b, 8);
        int nb = b8 - b0;
        int sv = ssrc[min(b0 + min(lane, max(nb - 1, 0)), EE - 1)];
#pragma unroll
        for (int p = 0; p < 2; ++p) {        // relation pass: r = p*4 + q
            int r = p * 4 + q;
            int beg = __shfl(b, r);          // full exec, per-lane index ok
            int end = __shfl(b, r + 1);
            int len = end - beg;
            int mx = max(max(__shfl(len, 0), __shfl(len, 16)),
                         max(__shfl(len, 32), __shfl(len, 48)));  // wave-uniform
            int begl = beg - b0;
            float a0 = 0.f, a1 = 0.f, a2 = 0.f, a3 = 0.f;
            float a4 = 0.f, a5 = 0.f, a6 = 0.f, a7 = 0.f;
            for (int j = 0; j < mx; j += 2) {   // uniform trip: full exec
                int e0 = begl + j, e1 = e0 + 1;
                int s0 = __shfl(sv, min(e0, 63));   // shfl ALWAYS full exec
                int s1 = __shfl(sv, min(e1, 63));
                if (j < len) {                       // loads predicated: no
                    if (e0 >= 64) s0 = ssrc[b0 + e0];// garbage traffic
                    uint4 u0 = h16[(size_t)s0 * 16 + ll];
                    a0 += bflo(u0.x); a1 += bfhi(u0.x);
                    a2 += bflo(u0.y); a3 += bfhi(u0.y);
                    a4 += bflo(u0.z); a5 += bfhi(u0.z);
                    a6 += bflo(u0.w); a7 += bfhi(u0.w);
                }
                if (j + 1 < len) {
                    if (e1 >= 64) s1 = ssrc[b0 + e1];
                    uint4 u1 = h16[(size_t)s1 * 16 + ll];
                    a0 += bflo(u1.x); a1 += bfhi(u1.x);
                    a2 += bflo(u1.y); a3 += bfhi(u1.y);
                    a4 += bflo(u1.z); a5 += bfhi(u1.z);
                    a6 += bflo(u1.w); a7 += bfhi(u1.w);
                }
            }
            float inv = 1.0f / (float)max(len, 1);
            uint4 o;
            o.x = f2bf(a0 * inv) | (f2bf(a1 * inv) << 16);
            o.y = f2bf(a2 * inv) | (f2bf(a3 * inv) << 16);
            o.z = f2bf(a4 * inv) | (f2bf(a5 * inv) << 16);
            o.w = f2bf(a6 * inv) | (f2bf(a7 * inv) << 16);
            *(uint4*)(&As[nl * LDW + (r * 16 + ll) * 8]) = o;
        }
    }
    // ---- root rows: cols [1024,1152) = chunks [128,144); 512 thr x 16B = 32 rows
    {
        int row = tid >> 4;                  // 0..31
        int cc = tid & 15;
        uint4 v = h16[(size_t)min(nbase + row, NN - 1) * 16 + cc];
        *(uint4*)(&As[row * LDW + (128 + cc) * 8]) = v;
    }
    __syncthreads();
    // ---- phase 2: MFMA. O=128 -> wave w: col-tile w, m-subtiles 0,1;
    //      O=64 -> wave w: col-tile w&3, m-subtile w>>2.
    constexpr int NTILE = O / 16;
    const int cw = w % NTILE;
    const int mt0 = (NTILE == 8) ? 0 : (w / NTILE);
    constexpr int NMT = (NTILE == 8) ? 2 : 1;
    const int lr = lane & 15, hi = lane >> 4;
    f32x4 acc[NMT] = {};
    const ushort* wcol = WT + (size_t)(cw * 16 + lr) * KTOT + hi * 8;
#pragma unroll
    for (int ks = 0; ks < 36; ++ks) {
        bf16x8 bb = *(const bf16x8*)(wcol + ks * 32);
        int g = ks * 4 + hi;
#pragma unroll
        for (int m = 0; m < NMT; ++m) {
            int row = (mt0 + m) * 16 + lr;
            bf16x8 a = *(const bf16x8*)(&As[row * LDW + g * 8]);
            acc[m] = __builtin_amdgcn_mfma_f32_16x16x32_bf16(a, bb, acc[m], 0, 0, 0);
        }
    }
    int col = cw * 16 + lr;
    float bs = bias[col];
#pragma unroll
    for (int m = 0; m < NMT; ++m) {
#pragma unroll
        for (int j = 0; j < 4; ++j) {        // C/D: col=lane&15, row=(lane>>4)*4+j
            int row = nbase + (mt0 + m) * 16 + hi * 4 + j;
            if (row >= NN) continue;
            float v = acc[m][j] + bs;
            if (RELU) v = fmaxf(v, 0.f);
            if (OUTF32) ((float*)outv)[(size_t)row * O + col] = v;
            else ((ushort*)outv)[(size_t)row * O + col] = (ushort)f2bf(v);
        }
    }
}

// ---------------- final log_softmax over 64 cols ----------------
__global__ void k_logsoftmax(const float* __restrict__ in, float* __restrict__ out) {
    int row = blockIdx.x * 4 + (threadIdx.x >> 6);
    int lane = threadIdx.x & 63;
    if (row >= NN) return;
    float v = in[(size_t)row * 64 + lane];
    float m = v;
#pragma unroll
    for (int off = 32; off; off >>= 1) m = fmaxf(m, __shfl_xor(m, off, 64));
    float e = expf(v - m);
    float s = e;
#pragma unroll
    for (int off = 32; off; off >>= 1) s += __shfl_xor(s, off, 64);
    out[(size_t)row * 64 + lane] = v - m - logf(s);
}

extern "C" void kernel_launch(void* const* d_in, const int* in_sizes, int n_in,
                              void* d_out, int out_size, void* d_ws, size_t ws_size,
                              hipStream_t stream) {
    const float* x  = (const float*)d_in[0];
    const int*   ei = (const int*)d_in[1];
    const int*   et = (const int*)d_in[2];
    const float* W[4]    = {(const float*)d_in[3], (const float*)d_in[6],
                            (const float*)d_in[9], (const float*)d_in[12]};
    const float* root[4] = {(const float*)d_in[4], (const float*)d_in[7],
                            (const float*)d_in[10], (const float*)d_in[13]};
    const float* bias[4] = {(const float*)d_in[5], (const float*)d_in[8],
                            (const float*)d_in[11], (const float*)d_in[14]};

    if (ws_size < WS_NEED) return;

    char* ws = (char*)d_ws;
    ushort* hb0  = (ushort*)(ws + OFF_HB0);
    ushort* hb1  = (ushort*)(ws + OFF_HB1);
    ushort* xb   = (ushort*)(ws + OFF_XB);
    float*  lg   = (float*)(ws + OFF_LG);
    ushort* WT   = (ushort*)(ws + OFF_WT);
    int*   offs  = (int*)(ws + OFF_OFFS);
    int*   cur   = (int*)(ws + OFF_CUR);
    int*   ssrc  = (int*)(ws + OFF_SRT);
    int*   bsums = (int*)(ws + OFF_BS);
    ushort* WTl[4] = {WT, WT + 147456, WT + 2 * 147456, WT + 3 * 147456};

    // one-time converts
    k_cvt<<<(NN * 32 + 255) / 256, 256, 0, stream>>>(x, xb);
    k_wt<<<128, 256, 0, stream>>>(W[0], root[0], WTl[0], 128);
    k_wt<<<128, 256, 0, stream>>>(W[1], root[1], WTl[1], 128);
    k_wt<<<128, 256, 0, stream>>>(W[2], root[2], WTl[2], 128);
    k_wt<<<64,  256, 0, stream>>>(W[3], root[3], WTl[3], 64);

    // edge sort by segment key s = dst*8 + etype
    hipMemsetAsync(cur, 0, RN * sizeof(int), stream);
    k_hist<<<(EE + 255) / 256, 256, 0, stream>>>(ei, et, cur);
    k_scan1<<<NBLK, 1024, 0, stream>>>(cur, offs, bsums);
    k_scan2<<<1, 1024, 0, stream>>>(bsums);
    k_scan3<<<NBLK, 1024, 0, stream>>>(offs, bsums);
    hipMemsetAsync(cur, 0, RN * sizeof(int), stream);
    k_scatter<<<(EE + 255) / 256, 256, 0, stream>>>(ei, et, offs, cur, ssrc);

    const int G = (NN + 31) / 32;   // 1563
    k_fused<128, true,  false><<<G, 512, 0, stream>>>(xb,  offs, ssrc, WTl[0], bias[0], hb0);
    k_fused<128, true,  false><<<G, 512, 0, stream>>>(hb0, offs, ssrc, WTl[1], bias[1], hb1);
    k_fused<128, true,  false><<<G, 512, 0, stream>>>(hb1, offs, ssrc, WTl[2], bias[2], hb0);
    k_fused<64,  false, true ><<<G, 512, 0, stream>>>(hb0, offs, ssrc, WTl[3], bias[3], lg);
    k_logsoftmax<<<(NN + 3) / 4, 256, 0, stream>>>(lg, (float*)d_out);
}

// Round 14
// 607.477 us; speedup vs baseline: 1.0875x; 1.0399x over previous
//
#include <hip/hip_runtime.h>
#include <math.h>

#define NN 50000
#define RR 8
#define EE 800000
#define RN 400000            // RR * NN
#define DIN 128
#define K1 1024              // RR * DIN
#define KTOT 1152            // K1 + DIN
#define NBLK 391             // ceil(RN / 1024)
#define LDW 1160             // LDS row width (elems) = 145 16B-chunks (ODD -> natural
                             // per-row bank rotation; NO XOR swizzle — R10 post-mortem)

// ---------------- workspace layout (bytes) ----------------
#define OFF_HB0  0UL           // h bf16: [NN][128] = 12,800,000
#define OFF_HB1  12800000UL    // h bf16: [NN][128] = 12,800,000
#define OFF_XB   25600000UL    // x bf16: [NN][128] = 12,800,000
#define OFF_LG   38400000UL    // logits f32: [NN][64] = 12,800,000
#define OFF_WT   51200000UL    // W^T bf16: 4 x 147456 elems = 1,179,648
#define OFF_OFFS 52379648UL    // offsets: (RN+1) ints -> 1,600,128
#define OFF_CUR  53979776UL    // cursor/hist: RN ints = 1,600,000
#define OFF_SRT  55579776UL    // sorted_src: EE ints = 3,200,000
#define OFF_BS   58779776UL    // block sums = 4,096
#define WS_NEED  58783872UL

typedef short bf16x8 __attribute__((ext_vector_type(8)));
typedef float f32x4 __attribute__((ext_vector_type(4)));

__device__ __forceinline__ unsigned f2bf(float f) {       // RNE f32 -> bf16 bits
    unsigned x = __float_as_uint(f);
    return (x + 0x7fffu + ((x >> 16) & 1u)) >> 16;
}
__device__ __forceinline__ float bflo(unsigned p) { return __uint_as_float(p << 16); }
__device__ __forceinline__ float bfhi(unsigned p) { return __uint_as_float(p & 0xffff0000u); }

// ---------------- one-time converts ----------------
__global__ void k_cvt(const float* __restrict__ x, ushort* __restrict__ xb) {
    int i = blockIdx.x * 256 + threadIdx.x;
    if (i >= NN * 32) return;                 // float4 granules
    float4 v = ((const float4*)x)[i];
    ushort4 o;
    o.x = (ushort)f2bf(v.x); o.y = (ushort)f2bf(v.y);
    o.z = (ushort)f2bf(v.z); o.w = (ushort)f2bf(v.w);
    ((ushort4*)xb)[i] = o;
}

// build W^T[o][k] bf16, k in [0,1152): k<1024 -> W[k>>7][k&127][o], else root[k-1024][o]
__global__ void k_wt(const float* __restrict__ W, const float* __restrict__ Rt,
                     ushort* __restrict__ WT, int O) {
    int o = blockIdx.x;
    for (int k = threadIdx.x; k < KTOT; k += 256) {
        float v = (k < K1)
            ? W[(size_t)(k >> 7) * 128 * O + (size_t)(k & 127) * O + o]
            : Rt[(size_t)(k - K1) * O + o];
        WT[(size_t)o * KTOT + k] = (ushort)f2bf(v);
    }
}

// ---------------- edge preprocessing (counting sort by s = dst*8 + r) ----------------
__global__ void k_hist(const int* __restrict__ ei, const int* __restrict__ et,
                       int* __restrict__ hist) {
    int e = blockIdx.x * blockDim.x + threadIdx.x;
    if (e >= EE) return;
    atomicAdd(&hist[ei[EE + e] * RR + et[e]], 1);
}

__global__ void k_scan1(const int* __restrict__ hist, int* __restrict__ offs,
                        int* __restrict__ bsums) {
    __shared__ int tmp[1024];
    int tid = threadIdx.x;
    int g = blockIdx.x * 1024 + tid;
    int v = (g < RN) ? hist[g] : 0;
    tmp[tid] = v;
    __syncthreads();
    for (int off = 1; off < 1024; off <<= 1) {
        int t = tmp[tid];
        if (tid >= off) t += tmp[tid - off];
        __syncthreads();
        tmp[tid] = t;
        __syncthreads();
    }
    if (g < RN) offs[g] = tmp[tid] - v;
    if (tid == 1023) bsums[blockIdx.x] = tmp[1023];
}

__global__ void k_scan2(int* __restrict__ bsums) {
    __shared__ int tmp[1024];
    int tid = threadIdx.x;
    int v = (tid < NBLK) ? bsums[tid] : 0;
    tmp[tid] = v;
    __syncthreads();
    for (int off = 1; off < 1024; off <<= 1) {
        int t = tmp[tid];
        if (tid >= off) t += tmp[tid - off];
        __syncthreads();
        tmp[tid] = t;
        __syncthreads();
    }
    if (tid < NBLK) bsums[tid] = tmp[tid] - v;
}

__global__ void k_scan3(int* __restrict__ offs, const int* __restrict__ bsums) {
    int g = blockIdx.x * 1024 + threadIdx.x;
    if (g < RN) offs[g] += bsums[blockIdx.x];
    else if (g == RN) offs[RN] = EE;
}

__global__ void k_scatter(const int* __restrict__ ei, const int* __restrict__ et,
                          const int* __restrict__ offs, int* __restrict__ cur,
                          int* __restrict__ ssrc) {
    int e = blockIdx.x * blockDim.x + threadIdx.x;
    if (e >= EE) return;
    int s = ei[EE + e] * RR + et[e];
    ssrc[offs[s] + atomicAdd(&cur[s], 1)] = ei[e];
}

// ---------------- fused layer: agg -> LDS -> MFMA, one barrier ----------------
// R14: R11's exact gather (unconditional clamped loads — R13's predication
// regressed: garbage loads were L2/L3 hits, predication only broke load
// pipelining) with 16-NODE blocks: LDS 37.1KB -> 4 blocks/CU x 8 waves = 32
// waves/CU at UNCHANGED VGPR (~52 <= 64 keeps 8 waves/SIMD; the untested
// quadrant — R12's occupancy test was confounded by its VGPR squeeze to 32).
// Grid 3125 = 50000/16 exact. Wave w: nodes 2w, 2w+1. Phase 2: O=128 -> 8
// waves <-> 8 col-tiles; O=64 -> 4 waves.
template<int O, bool RELU, bool OUTF32>
__global__ __launch_bounds__(512) void k_fused(
        const ushort* __restrict__ hb, const int* __restrict__ offs,
        const int* __restrict__ ssrc, const ushort* __restrict__ WT,
        const float* __restrict__ bias, void* __restrict__ outv) {
    __shared__ ushort As[16 * LDW];          // 37,120 B
    const int tid = threadIdx.x;
    const int lane = tid & 63;
    const int w = tid >> 6;                  // 0..7
    const int q = lane >> 4;                 // quarter 0..3 = relation slot
    const int ll = lane & 15;                // 16B chunk within row
    const int nbase = blockIdx.x * 16;
    const uint4* h16 = (const uint4*)hb;     // h row = 16 uint4

    // ---- phase 1: gather/aggregate 2 nodes per wave
    for (int i = 0; i < 2; ++i) {            // wave-uniform
        int nl = w * 2 + i;
        int n = nbase + nl;                  // exact grid: n < NN always
        int b = offs[n * 8 + min(lane, 8)];
        int b0 = __shfl(b, 0), b8 = __shfl(b, 8);
        int nb = b8 - b0;
        int sv = ssrc[min(b0 + min(lane, max(nb - 1, 0)), EE - 1)];
#pragma unroll
        for (int p = 0; p < 2; ++p) {        // relation pass: r = p*4 + q
            int r = p * 4 + q;
            int beg = __shfl(b, r);          // full exec, per-lane index ok
            int end = __shfl(b, r + 1);
            int len = end - beg;
            int mx = max(max(__shfl(len, 0), __shfl(len, 16)),
                         max(__shfl(len, 32), __shfl(len, 48)));  // wave-uniform
            int begl = beg - b0;
            float a0 = 0.f, a1 = 0.f, a2 = 0.f, a3 = 0.f;
            float a4 = 0.f, a5 = 0.f, a6 = 0.f, a7 = 0.f;
            for (int j = 0; j < mx; j += 2) {   // uniform trip: full exec
                int e0 = begl + j, e1 = e0 + 1;
                int s0 = __shfl(sv, min(e0, 63));   // shfl ALWAYS full exec
                int s1 = __shfl(sv, min(e1, 63));
                if (e1 >= 64) {                 // rare: node degree > 64
                    s0 = ssrc[min(b0 + e0, EE - 1)];
                    s1 = ssrc[min(b0 + e1, EE - 1)];
                }
                uint4 u0 = h16[(size_t)s0 * 16 + ll];   // unconditional:
                uint4 u1 = h16[(size_t)s1 * 16 + ll];   // L2/L3 hits, pipelined
                if (j < len) {
                    a0 += bflo(u0.x); a1 += bfhi(u0.x);
                    a2 += bflo(u0.y); a3 += bfhi(u0.y);
                    a4 += bflo(u0.z); a5 += bfhi(u0.z);
                    a6 += bflo(u0.w); a7 += bfhi(u0.w);
                }
                if (j + 1 < len) {
                    a0 += bflo(u1.x); a1 += bfhi(u1.x);
                    a2 += bflo(u1.y); a3 += bfhi(u1.y);
                    a4 += bflo(u1.z); a5 += bfhi(u1.z);
                    a6 += bflo(u1.w); a7 += bfhi(u1.w);
                }
            }
            float inv = 1.0f / (float)max(len, 1);
            uint4 o;
            o.x = f2bf(a0 * inv) | (f2bf(a1 * inv) << 16);
            o.y = f2bf(a2 * inv) | (f2bf(a3 * inv) << 16);
            o.z = f2bf(a4 * inv) | (f2bf(a5 * inv) << 16);
            o.w = f2bf(a6 * inv) | (f2bf(a7 * inv) << 16);
            *(uint4*)(&As[nl * LDW + (r * 16 + ll) * 8]) = o;
        }
    }
    // ---- root rows: cols [1024,1152) = chunks [128,144); 256 thr x 16B = 16 rows
    if (tid < 256) {
        int row = tid >> 4;                  // 0..15
        int cc = tid & 15;
        uint4 v = h16[(size_t)(nbase + row) * 16 + cc];
        *(uint4*)(&As[row * LDW + (128 + cc) * 8]) = v;
    }
    __syncthreads();
    // ---- phase 2: MFMA. O=128 -> 8 waves <-> 8 col-tiles; O=64 -> waves 0..3.
    constexpr int NW2 = O / 16;              // 8 or 4
    if (w < NW2) {
        const int lr = lane & 15, hi = lane >> 4;
        f32x4 acc = {};
        const ushort* wcol = WT + (size_t)(w * 16 + lr) * KTOT + hi * 8;
#pragma unroll
        for (int ks = 0; ks < 36; ++ks) {
            bf16x8 bb = *(const bf16x8*)(wcol + ks * 32);
            int g = ks * 4 + hi;
            bf16x8 a = *(const bf16x8*)(&As[lr * LDW + g * 8]);
            acc = __builtin_amdgcn_mfma_f32_16x16x32_bf16(a, bb, acc, 0, 0, 0);
        }
        int col = w * 16 + lr;
        float bs = bias[col];
#pragma unroll
        for (int j = 0; j < 4; ++j) {        // C/D: col=lane&15, row=(lane>>4)*4+j
            int row = nbase + hi * 4 + j;
            float v = acc[j] + bs;
            if (RELU) v = fmaxf(v, 0.f);
            if (OUTF32) ((float*)outv)[(size_t)row * O + col] = v;
            else ((ushort*)outv)[(size_t)row * O + col] = (ushort)f2bf(v);
        }
    }
}

// ---------------- final log_softmax over 64 cols ----------------
__global__ void k_logsoftmax(const float* __restrict__ in, float* __restrict__ out) {
    int row = blockIdx.x * 4 + (threadIdx.x >> 6);
    int lane = threadIdx.x & 63;
    if (row >= NN) return;
    float v = in[(size_t)row * 64 + lane];
    float m = v;
#pragma unroll
    for (int off = 32; off; off >>= 1) m = fmaxf(m, __shfl_xor(m, off, 64));
    float e = expf(v - m);
    float s = e;
#pragma unroll
    for (int off = 32; off; off >>= 1) s += __shfl_xor(s, off, 64);
    out[(size_t)row * 64 + lane] = v - m - logf(s);
}

extern "C" void kernel_launch(void* const* d_in, const int* in_sizes, int n_in,
                              void* d_out, int out_size, void* d_ws, size_t ws_size,
                              hipStream_t stream) {
    const float* x  = (const float*)d_in[0];
    const int*   ei = (const int*)d_in[1];
    const int*   et = (const int*)d_in[2];
    const float* W[4]    = {(const float*)d_in[3], (const float*)d_in[6],
                            (const float*)d_in[9], (const float*)d_in[12]};
    const float* root[4] = {(const float*)d_in[4], (const float*)d_in[7],
                            (const float*)d_in[10], (const float*)d_in[13]};
    const float* bias[4] = {(const float*)d_in[5], (const float*)d_in[8],
                            (const float*)d_in[11], (const float*)d_in[14]};

    if (ws_size < WS_NEED) return;

    char* ws = (char*)d_ws;
    ushort* hb0  = (ushort*)(ws + OFF_HB0);
    ushort* hb1  = (ushort*)(ws + OFF_HB1);
    ushort* xb   = (ushort*)(ws + OFF_XB);
    float*  lg   = (float*)(ws + OFF_LG);
    ushort* WT   = (ushort*)(ws + OFF_WT);
    int*   offs  = (int*)(ws + OFF_OFFS);
    int*   cur   = (int*)(ws + OFF_CUR);
    int*   ssrc  = (int*)(ws + OFF_SRT);
    int*   bsums = (int*)(ws + OFF_BS);
    ushort* WTl[4] = {WT, WT + 147456, WT + 2 * 147456, WT + 3 * 147456};

    // one-time converts
    k_cvt<<<(NN * 32 + 255) / 256, 256, 0, stream>>>(x, xb);
    k_wt<<<128, 256, 0, stream>>>(W[0], root[0], WTl[0], 128);
    k_wt<<<128, 256, 0, stream>>>(W[1], root[1], WTl[1], 128);
    k_wt<<<128, 256, 0, stream>>>(W[2], root[2], WTl[2], 128);
    k_wt<<<64,  256, 0, stream>>>(W[3], root[3], WTl[3], 64);

    // edge sort by segment key s = dst*8 + etype
    hipMemsetAsync(cur, 0, RN * sizeof(int), stream);
    k_hist<<<(EE + 255) / 256, 256, 0, stream>>>(ei, et, cur);
    k_scan1<<<NBLK, 1024, 0, stream>>>(cur, offs, bsums);
    k_scan2<<<1, 1024, 0, stream>>>(bsums);
    k_scan3<<<NBLK, 1024, 0, stream>>>(offs, bsums);
    hipMemsetAsync(cur, 0, RN * sizeof(int), stream);
    k_scatter<<<(EE + 255) / 256, 256, 0, stream>>>(ei, et, offs, cur, ssrc);

    const int G = NN / 16;   // 3125 exact
    k_fused<128, true,  false><<<G, 512, 0, stream>>>(xb,  offs, ssrc, WTl[0], bias[0], hb0);
    k_fused<128, true,  false><<<G, 512, 0, stream>>>(hb0, offs, ssrc, WTl[1], bias[1], hb1);
    k_fused<128, true,  false><<<G, 512, 0, stream>>>(hb1, offs, ssrc, WTl[2], bias[2], hb0);
    k_fused<64,  false, true ><<<G, 512, 0, stream>>>(hb0, offs, ssrc, WTl[3], bias[3], lg);
    k_logsoftmax<<<(NN + 3) / 4, 256, 0, stream>>>(lg, (float*)d_out);
}

// Round 15
// 539.447 us; speedup vs baseline: 1.2247x; 1.1261x over previous
//
#include <hip/hip_runtime.h>
#include <math.h>

#define NN 50000
#define RR 8
#define EE 800000
#define RN 400000            // RR * NN
#define DIN 128
#define K1 1024              // RR * DIN
#define KTOT 1152            // K1 + DIN
#define NBLK 391             // ceil(RN / 1024)
#define LDW 1160             // LDS row width (elems) = 145 16B-chunks (ODD -> natural
                             // per-row bank rotation; NO XOR swizzle — R10 post-mortem)

// ---------------- workspace layout (bytes) ----------------
#define OFF_HB0  0UL           // h bf16: [NN][128] = 12,800,000
#define OFF_HB1  12800000UL    // h bf16: [NN][128] = 12,800,000
#define OFF_XB   25600000UL    // x bf16: [NN][128] = 12,800,000
#define OFF_LG   38400000UL    // logits f32: [NN][64] = 12,800,000
#define OFF_WT   51200000UL    // W^T bf16: 4 x 147456 elems = 1,179,648
#define OFF_OFFS 52379648UL    // offsets: (RN+1) ints -> 1,600,128
#define OFF_CUR  53979776UL    // cursor/hist: RN ints = 1,600,000
#define OFF_SRT  55579776UL    // sorted_src: EE ints = 3,200,000
#define OFF_BS   58779776UL    // block sums = 4,096
#define WS_NEED  58783872UL

typedef short bf16x8 __attribute__((ext_vector_type(8)));
typedef float f32x4 __attribute__((ext_vector_type(4)));

__device__ __forceinline__ unsigned f2bf(float f) {       // RNE f32 -> bf16 bits
    unsigned x = __float_as_uint(f);
    return (x + 0x7fffu + ((x >> 16) & 1u)) >> 16;
}
__device__ __forceinline__ float bflo(unsigned p) { return __uint_as_float(p << 16); }
__device__ __forceinline__ float bfhi(unsigned p) { return __uint_as_float(p & 0xffff0000u); }

// ---------------- one-time converts ----------------
__global__ void k_cvt(const float* __restrict__ x, ushort* __restrict__ xb) {
    int i = blockIdx.x * 256 + threadIdx.x;
    if (i >= NN * 32) return;                 // float4 granules
    float4 v = ((const float4*)x)[i];
    ushort4 o;
    o.x = (ushort)f2bf(v.x); o.y = (ushort)f2bf(v.y);
    o.z = (ushort)f2bf(v.z); o.w = (ushort)f2bf(v.w);
    ((ushort4*)xb)[i] = o;
}

// build W^T[o][k] bf16, k in [0,1152): k<1024 -> W[k>>7][k&127][o], else root[k-1024][o]
__global__ void k_wt(const float* __restrict__ W, const float* __restrict__ Rt,
                     ushort* __restrict__ WT, int O) {
    int o = blockIdx.x;
    for (int k = threadIdx.x; k < KTOT; k += 256) {
        float v = (k < K1)
            ? W[(size_t)(k >> 7) * 128 * O + (size_t)(k & 127) * O + o]
            : Rt[(size_t)(k - K1) * O + o];
        WT[(size_t)o * KTOT + k] = (ushort)f2bf(v);
    }
}

// ---------------- edge preprocessing (counting sort by s = dst*8 + r) ----------------
__global__ void k_hist(const int* __restrict__ ei, const int* __restrict__ et,
                       int* __restrict__ hist) {
    int e = blockIdx.x * blockDim.x + threadIdx.x;
    if (e >= EE) return;
    atomicAdd(&hist[ei[EE + e] * RR + et[e]], 1);
}

__global__ void k_scan1(const int* __restrict__ hist, int* __restrict__ offs,
                        int* __restrict__ bsums) {
    __shared__ int tmp[1024];
    int tid = threadIdx.x;
    int g = blockIdx.x * 1024 + tid;
    int v = (g < RN) ? hist[g] : 0;
    tmp[tid] = v;
    __syncthreads();
    for (int off = 1; off < 1024; off <<= 1) {
        int t = tmp[tid];
        if (tid >= off) t += tmp[tid - off];
        __syncthreads();
        tmp[tid] = t;
        __syncthreads();
    }
    if (g < RN) offs[g] = tmp[tid] - v;
    if (tid == 1023) bsums[blockIdx.x] = tmp[1023];
}

__global__ void k_scan2(int* __restrict__ bsums) {
    __shared__ int tmp[1024];
    int tid = threadIdx.x;
    int v = (tid < NBLK) ? bsums[tid] : 0;
    tmp[tid] = v;
    __syncthreads();
    for (int off = 1; off < 1024; off <<= 1) {
        int t = tmp[tid];
        if (tid >= off) t += tmp[tid - off];
        __syncthreads();
        tmp[tid] = t;
        __syncthreads();
    }
    if (tid < NBLK) bsums[tid] = tmp[tid] - v;
}

__global__ void k_scan3(int* __restrict__ offs, const int* __restrict__ bsums) {
    int g = blockIdx.x * 1024 + threadIdx.x;
    if (g < RN) offs[g] += bsums[blockIdx.x];
    else if (g == RN) offs[RN] = EE;
}

__global__ void k_scatter(const int* __restrict__ ei, const int* __restrict__ et,
                          const int* __restrict__ offs, int* __restrict__ cur,
                          int* __restrict__ ssrc) {
    int e = blockIdx.x * blockDim.x + threadIdx.x;
    if (e >= EE) return;
    int s = ei[EE + e] * RR + et[e];
    ssrc[offs[s] + atomicAdd(&cur[s], 1)] = ei[e];
}

// ---------------- fused layer: agg -> LDS -> MFMA, one barrier ----------------
// R15 = R11 (champion: 32-node block, 512 thr / 8 waves, VGPR free-running;
// every VGPR-32 variant — R6/R12/R14 — lost regardless of occupancy) with ONE
// change: 4-DEEP edge unroll. Gather is bound by dependent wait rounds
// (FETCH invariant across R11/R13), so issue 4 shfl + 4 unconditional uint4
// gathers per iteration -> wait rounds per wave 17 -> ~9. LDS caps us at 2
// blocks/CU (4 waves/SIMD), so VGPR up to 128 is occupancy-free headroom.
template<int O, bool RELU, bool OUTF32>
__global__ __launch_bounds__(512) void k_fused(
        const ushort* __restrict__ hb, const int* __restrict__ offs,
        const int* __restrict__ ssrc, const ushort* __restrict__ WT,
        const float* __restrict__ bias, void* __restrict__ outv) {
    __shared__ ushort As[32 * LDW];
    const int tid = threadIdx.x;
    const int lane = tid & 63;
    const int w = tid >> 6;                  // 0..7
    const int q = lane >> 4;                 // quarter 0..3 = relation slot
    const int ll = lane & 15;                // 16B chunk within row
    const int nbase = blockIdx.x * 32;
    const uint4* h16 = (const uint4*)hb;     // h row = 16 uint4

    // ---- phase 1: gather/aggregate 4 nodes per wave
    for (int i = 0; i < 4; ++i) {            // wave-uniform
        int nl = w * 4 + i;
        int n = min(nbase + nl, NN - 1);     // clamp tail (junk rows masked later)
        int b = offs[n * 8 + min(lane, 8)];
        int b0 = __shfl(b, 0), b8 = __shfl(b, 8);
        int nb = b8 - b0;
        int sv = ssrc[min(b0 + min(lane, max(nb - 1, 0)), EE - 1)];
#pragma unroll
        for (int p = 0; p < 2; ++p) {        // relation pass: r = p*4 + q
            int r = p * 4 + q;
            int beg = __shfl(b, r);          // full exec, per-lane index ok
            int end = __shfl(b, r + 1);
            int len = end - beg;
            int mx = max(max(__shfl(len, 0), __shfl(len, 16)),
                         max(__shfl(len, 32), __shfl(len, 48)));  // wave-uniform
            int begl = beg - b0;
            float a0 = 0.f, a1 = 0.f, a2 = 0.f, a3 = 0.f;
            float a4 = 0.f, a5 = 0.f, a6 = 0.f, a7 = 0.f;
            for (int j = 0; j < mx; j += 4) {   // uniform trip: full exec
                int e0 = begl + j;
                int s0 = __shfl(sv, min(e0, 63));       // shfl ALWAYS full exec
                int s1 = __shfl(sv, min(e0 + 1, 63));
                int s2 = __shfl(sv, min(e0 + 2, 63));
                int s3 = __shfl(sv, min(e0 + 3, 63));
                if (e0 + 3 >= 64) {              // rare: node degree > 64
                    s0 = ssrc[min(b0 + e0, EE - 1)];
                    s1 = ssrc[min(b0 + e0 + 1, EE - 1)];
                    s2 = ssrc[min(b0 + e0 + 2, EE - 1)];
                    s3 = ssrc[min(b0 + e0 + 3, EE - 1)];
                }
                uint4 u0 = h16[(size_t)s0 * 16 + ll];   // 4 loads in flight,
                uint4 u1 = h16[(size_t)s1 * 16 + ll];   // unconditional (L2/L3
                uint4 u2 = h16[(size_t)s2 * 16 + ll];   // hits; R13: guarding
                uint4 u3 = h16[(size_t)s3 * 16 + ll];   // loads regressed)
                if (j < len) {
                    a0 += bflo(u0.x); a1 += bfhi(u0.x);
                    a2 += bflo(u0.y); a3 += bfhi(u0.y);
                    a4 += bflo(u0.z); a5 += bfhi(u0.z);
                    a6 += bflo(u0.w); a7 += bfhi(u0.w);
                }
                if (j + 1 < len) {
                    a0 += bflo(u1.x); a1 += bfhi(u1.x);
                    a2 += bflo(u1.y); a3 += bfhi(u1.y);
                    a4 += bflo(u1.z); a5 += bfhi(u1.z);
                    a6 += bflo(u1.w); a7 += bfhi(u1.w);
                }
                if (j + 2 < len) {
                    a0 += bflo(u2.x); a1 += bfhi(u2.x);
                    a2 += bflo(u2.y); a3 += bfhi(u2.y);
                    a4 += bflo(u2.z); a5 += bfhi(u2.z);
                    a6 += bflo(u2.w); a7 += bfhi(u2.w);
                }
                if (j + 3 < len) {
                    a0 += bflo(u3.x); a1 += bfhi(u3.x);
                    a2 += bflo(u3.y); a3 += bfhi(u3.y);
                    a4 += bflo(u3.z); a5 += bfhi(u3.z);
                    a6 += bflo(u3.w); a7 += bfhi(u3.w);
                }
            }
            float inv = 1.0f / (float)max(len, 1);
            uint4 o;
            o.x = f2bf(a0 * inv) | (f2bf(a1 * inv) << 16);
            o.y = f2bf(a2 * inv) | (f2bf(a3 * inv) << 16);
            o.z = f2bf(a4 * inv) | (f2bf(a5 * inv) << 16);
            o.w = f2bf(a6 * inv) | (f2bf(a7 * inv) << 16);
            *(uint4*)(&As[nl * LDW + (r * 16 + ll) * 8]) = o;
        }
    }
    // ---- root rows: cols [1024,1152) = chunks [128,144); 512 thr x 16B = 32 rows
    {
        int row = tid >> 4;                  // 0..31
        int cc = tid & 15;
        uint4 v = h16[(size_t)min(nbase + row, NN - 1) * 16 + cc];
        *(uint4*)(&As[row * LDW + (128 + cc) * 8]) = v;
    }
    __syncthreads();
    // ---- phase 2: MFMA. O=128 -> wave w: col-tile w, m-subtiles 0,1;
    //      O=64 -> wave w: col-tile w&3, m-subtile w>>2.
    constexpr int NTILE = O / 16;
    const int cw = w % NTILE;
    const int mt0 = (NTILE == 8) ? 0 : (w / NTILE);
    constexpr int NMT = (NTILE == 8) ? 2 : 1;
    const int lr = lane & 15, hi = lane >> 4;
    f32x4 acc[NMT] = {};
    const ushort* wcol = WT + (size_t)(cw * 16 + lr) * KTOT + hi * 8;
#pragma unroll
    for (int ks = 0; ks < 36; ++ks) {
        bf16x8 bb = *(const bf16x8*)(wcol + ks * 32);
        int g = ks * 4 + hi;
#pragma unroll
        for (int m = 0; m < NMT; ++m) {
            int row = (mt0 + m) * 16 + lr;
            bf16x8 a = *(const bf16x8*)(&As[row * LDW + g * 8]);
            acc[m] = __builtin_amdgcn_mfma_f32_16x16x32_bf16(a, bb, acc[m], 0, 0, 0);
        }
    }
    int col = cw * 16 + lr;
    float bs = bias[col];
#pragma unroll
    for (int m = 0; m < NMT; ++m) {
#pragma unroll
        for (int j = 0; j < 4; ++j) {        // C/D: col=lane&15, row=(lane>>4)*4+j
            int row = nbase + (mt0 + m) * 16 + hi * 4 + j;
            if (row >= NN) continue;
            float v = acc[m][j] + bs;
            if (RELU) v = fmaxf(v, 0.f);
            if (OUTF32) ((float*)outv)[(size_t)row * O + col] = v;
            else ((ushort*)outv)[(size_t)row * O + col] = (ushort)f2bf(v);
        }
    }
}

// ---------------- final log_softmax over 64 cols ----------------
__global__ void k_logsoftmax(const float* __restrict__ in, float* __restrict__ out) {
    int row = blockIdx.x * 4 + (threadIdx.x >> 6);
    int lane = threadIdx.x & 63;
    if (row >= NN) return;
    float v = in[(size_t)row * 64 + lane];
    float m = v;
#pragma unroll
    for (int off = 32; off; off >>= 1) m = fmaxf(m, __shfl_xor(m, off, 64));
    float e = expf(v - m);
    float s = e;
#pragma unroll
    for (int off = 32; off; off >>= 1) s += __shfl_xor(s, off, 64);
    out[(size_t)row * 64 + lane] = v - m - logf(s);
}

extern "C" void kernel_launch(void* const* d_in, const int* in_sizes, int n_in,
                              void* d_out, int out_size, void* d_ws, size_t ws_size,
                              hipStream_t stream) {
    const float* x  = (const float*)d_in[0];
    const int*   ei = (const int*)d_in[1];
    const int*   et = (const int*)d_in[2];
    const float* W[4]    = {(const float*)d_in[3], (const float*)d_in[6],
                            (const float*)d_in[9], (const float*)d_in[12]};
    const float* root[4] = {(const float*)d_in[4], (const float*)d_in[7],
                            (const float*)d_in[10], (const float*)d_in[13]};
    const float* bias[4] = {(const float*)d_in[5], (const float*)d_in[8],
                            (const float*)d_in[11], (const float*)d_in[14]};

    if (ws_size < WS_NEED) return;

    char* ws = (char*)d_ws;
    ushort* hb0  = (ushort*)(ws + OFF_HB0);
    ushort* hb1  = (ushort*)(ws + OFF_HB1);
    ushort* xb   = (ushort*)(ws + OFF_XB);
    float*  lg   = (float*)(ws + OFF_LG);
    ushort* WT   = (ushort*)(ws + OFF_WT);
    int*   offs  = (int*)(ws + OFF_OFFS);
    int*   cur   = (int*)(ws + OFF_CUR);
    int*   ssrc  = (int*)(ws + OFF_SRT);
    int*   bsums = (int*)(ws + OFF_BS);
    ushort* WTl[4] = {WT, WT + 147456, WT + 2 * 147456, WT + 3 * 147456};

    // one-time converts
    k_cvt<<<(NN * 32 + 255) / 256, 256, 0, stream>>>(x, xb);
    k_wt<<<128, 256, 0, stream>>>(W[0], root[0], WTl[0], 128);
    k_wt<<<128, 256, 0, stream>>>(W[1], root[1], WTl[1], 128);
    k_wt<<<128, 256, 0, stream>>>(W[2], root[2], WTl[2], 128);
    k_wt<<<64,  256, 0, stream>>>(W[3], root[3], WTl[3], 64);

    // edge sort by segment key s = dst*8 + etype
    hipMemsetAsync(cur, 0, RN * sizeof(int), stream);
    k_hist<<<(EE + 255) / 256, 256, 0, stream>>>(ei, et, cur);
    k_scan1<<<NBLK, 1024, 0, stream>>>(cur, offs, bsums);
    k_scan2<<<1, 1024, 0, stream>>>(bsums);
    k_scan3<<<NBLK, 1024, 0, stream>>>(offs, bsums);
    hipMemsetAsync(cur, 0, RN * sizeof(int), stream);
    k_scatter<<<(EE + 255) / 256, 256, 0, stream>>>(ei, et, offs, cur, ssrc);

    const int G = (NN + 31) / 32;   // 1563
    k_fused<128, true,  false><<<G, 512, 0, stream>>>(xb,  offs, ssrc, WTl[0], bias[0], hb0);
    k_fused<128, true,  false><<<G, 512, 0, stream>>>(hb0, offs, ssrc, WTl[1], bias[1], hb1);
    k_fused<128, true,  false><<<G, 512, 0, stream>>>(hb1, offs, ssrc, WTl[2], bias[2], hb0);
    k_fused<64,  false, true ><<<G, 512, 0, stream>>>(hb0, offs, ssrc, WTl[3], bias[3], lg);
    k_logsoftmax<<<(NN + 3) / 4, 256, 0, stream>>>(lg, (float*)d_out);
}

// Round 16
// 519.035 us; speedup vs baseline: 1.2729x; 1.0393x over previous
//
#include <hip/hip_runtime.h>
#include <math.h>

#define NN 50000
#define RR 8
#define EE 800000
#define RN 400000            // RR * NN
#define DIN 128
#define K1 1024              // RR * DIN
#define KTOT 1152            // K1 + DIN
#define NBLK 391             // ceil(RN / 1024)
#define LDW 1160             // LDS row width (elems) = 145 16B-chunks (ODD -> natural
                             // per-row bank rotation; NO XOR swizzle — R10 post-mortem)

// ---------------- workspace layout (bytes) ----------------
#define OFF_HB0  0UL           // h bf16: [NN][128] = 12,800,000
#define OFF_HB1  12800000UL    // h bf16: [NN][128] = 12,800,000
#define OFF_XB   25600000UL    // x bf16: [NN][128] = 12,800,000
#define OFF_LG   38400000UL    // logits f32: [NN][64] = 12,800,000
#define OFF_WT   51200000UL    // W^T bf16: 4 x 147456 elems = 1,179,648
#define OFF_OFFS 52379648UL    // offsets: (RN+1) ints -> 1,600,128
#define OFF_CUR  53979776UL    // cursor/hist: RN ints = 1,600,000
#define OFF_SRT  55579776UL    // sorted_src: EE ints = 3,200,000
#define OFF_BS   58779776UL    // block sums = 4,096
#define WS_NEED  58783872UL

typedef short bf16x8 __attribute__((ext_vector_type(8)));
typedef float f32x4 __attribute__((ext_vector_type(4)));

__device__ __forceinline__ unsigned f2bf(float f) {       // RNE f32 -> bf16 bits
    unsigned x = __float_as_uint(f);
    return (x + 0x7fffu + ((x >> 16) & 1u)) >> 16;
}
__device__ __forceinline__ float bflo(unsigned p) { return __uint_as_float(p << 16); }
__device__ __forceinline__ float bfhi(unsigned p) { return __uint_as_float(p & 0xffff0000u); }

// ---------------- one-time converts ----------------
__global__ void k_cvt(const float* __restrict__ x, ushort* __restrict__ xb) {
    int i = blockIdx.x * 256 + threadIdx.x;
    if (i >= NN * 32) return;                 // float4 granules
    float4 v = ((const float4*)x)[i];
    ushort4 o;
    o.x = (ushort)f2bf(v.x); o.y = (ushort)f2bf(v.y);
    o.z = (ushort)f2bf(v.z); o.w = (ushort)f2bf(v.w);
    ((ushort4*)xb)[i] = o;
}

// build W^T[o][k] bf16, k in [0,1152): k<1024 -> W[k>>7][k&127][o], else root[k-1024][o]
__global__ void k_wt(const float* __restrict__ W, const float* __restrict__ Rt,
                     ushort* __restrict__ WT, int O) {
    int o = blockIdx.x;
    for (int k = threadIdx.x; k < KTOT; k += 256) {
        float v = (k < K1)
            ? W[(size_t)(k >> 7) * 128 * O + (size_t)(k & 127) * O + o]
            : Rt[(size_t)(k - K1) * O + o];
        WT[(size_t)o * KTOT + k] = (ushort)f2bf(v);
    }
}

// ---------------- edge preprocessing (counting sort by s = dst*8 + r) ----------------
__global__ void k_hist(const int* __restrict__ ei, const int* __restrict__ et,
                       int* __restrict__ hist) {
    int e = blockIdx.x * blockDim.x + threadIdx.x;
    if (e >= EE) return;
    atomicAdd(&hist[ei[EE + e] * RR + et[e]], 1);
}

__global__ void k_scan1(const int* __restrict__ hist, int* __restrict__ offs,
                        int* __restrict__ bsums) {
    __shared__ int tmp[1024];
    int tid = threadIdx.x;
    int g = blockIdx.x * 1024 + tid;
    int v = (g < RN) ? hist[g] : 0;
    tmp[tid] = v;
    __syncthreads();
    for (int off = 1; off < 1024; off <<= 1) {
        int t = tmp[tid];
        if (tid >= off) t += tmp[tid - off];
        __syncthreads();
        tmp[tid] = t;
        __syncthreads();
    }
    if (g < RN) offs[g] = tmp[tid] - v;
    if (tid == 1023) bsums[blockIdx.x] = tmp[1023];
}

__global__ void k_scan2(int* __restrict__ bsums) {
    __shared__ int tmp[1024];
    int tid = threadIdx.x;
    int v = (tid < NBLK) ? bsums[tid] : 0;
    tmp[tid] = v;
    __syncthreads();
    for (int off = 1; off < 1024; off <<= 1) {
        int t = tmp[tid];
        if (tid >= off) t += tmp[tid - off];
        __syncthreads();
        tmp[tid] = t;
        __syncthreads();
    }
    if (tid < NBLK) bsums[tid] = tmp[tid] - v;
}

__global__ void k_scan3(int* __restrict__ offs, const int* __restrict__ bsums) {
    int g = blockIdx.x * 1024 + threadIdx.x;
    if (g < RN) offs[g] += bsums[blockIdx.x];
    else if (g == RN) offs[RN] = EE;
}

__global__ void k_scatter(const int* __restrict__ ei, const int* __restrict__ et,
                          const int* __restrict__ offs, int* __restrict__ cur,
                          int* __restrict__ ssrc) {
    int e = blockIdx.x * blockDim.x + threadIdx.x;
    if (e >= EE) return;
    int s = ei[EE + e] * RR + et[e];
    ssrc[offs[s] + atomicAdd(&cur[s], 1)] = ei[e];
}

// ---------------- fused layer: agg -> LDS -> MFMA, one barrier ----------------
// R16 = R15 (champion) + CHAIN INTERLEAVE: the 8 per-wave (node,pass) gather
// chains were serial; now 2 nodes (A,B) processed concurrently per iteration —
// lanes 0-31 carry A's boundaries, 32-63 B's (one offs load), two sv register
// files, shared uniform trip count, 8 gathers in flight per round (4/node).
// Wait rounds per wave: ~11 -> ~6.4. All __shfl at FULL exec (uniform trips,
// clamped indices); loads unconditional (R13: predication regressed). VGPR
// headroom: LDS caps 2 blocks/CU = 4 waves/SIMD, free up to 128 VGPRs.
template<int O, bool RELU, bool OUTF32>
__global__ __launch_bounds__(512) void k_fused(
        const ushort* __restrict__ hb, const int* __restrict__ offs,
        const int* __restrict__ ssrc, const ushort* __restrict__ WT,
        const float* __restrict__ bias, void* __restrict__ outv) {
    __shared__ ushort As[32 * LDW];
    const int tid = threadIdx.x;
    const int lane = tid & 63;
    const int w = tid >> 6;                  // 0..7
    const int q = lane >> 4;                 // quarter 0..3 = relation slot
    const int ll = lane & 15;                // 16B chunk within row
    const int nbase = blockIdx.x * 32;
    const uint4* h16 = (const uint4*)hb;     // h row = 16 uint4

    // ---- phase 1: 2 node-pairs per wave, A/B chains interleaved
    for (int i = 0; i < 2; ++i) {            // wave-uniform
        int nlA = w * 4 + i * 2;
        int nlB = nlA + 1;
        int nA = min(nbase + nlA, NN - 1);   // clamp tail (junk masked later)
        int nB = min(nbase + nlB, NN - 1);
        // one offs load: lanes 0-31 node A bounds, lanes 32-63 node B bounds
        int b = offs[((lane < 32) ? nA : nB) * 8 + min(lane & 31, 8)];
        int b0A = __shfl(b, 0),  b8A = __shfl(b, 8);
        int b0B = __shfl(b, 32), b8B = __shfl(b, 40);
        int nbA = b8A - b0A, nbB = b8B - b0B;
        int svA = ssrc[min(b0A + min(lane, max(nbA - 1, 0)), EE - 1)];
        int svB = ssrc[min(b0B + min(lane, max(nbB - 1, 0)), EE - 1)];
#pragma unroll
        for (int p = 0; p < 2; ++p) {        // relation pass: r = p*4 + q
            int r = p * 4 + q;
            int begA = __shfl(b, r),      endA = __shfl(b, r + 1);
            int begB = __shfl(b, 32 + r), endB = __shfl(b, 32 + r + 1);
            int lenA = endA - begA, lenB = endB - begB;
            int mxA = max(max(__shfl(lenA, 0), __shfl(lenA, 16)),
                          max(__shfl(lenA, 32), __shfl(lenA, 48)));
            int mxB = max(max(__shfl(lenB, 0), __shfl(lenB, 16)),
                          max(__shfl(lenB, 32), __shfl(lenB, 48)));
            int mx = max(mxA, mxB);          // wave-uniform trip count
            int beglA = begA - b0A, beglB = begB - b0B;
            float aA0 = 0.f, aA1 = 0.f, aA2 = 0.f, aA3 = 0.f;
            float aA4 = 0.f, aA5 = 0.f, aA6 = 0.f, aA7 = 0.f;
            float aB0 = 0.f, aB1 = 0.f, aB2 = 0.f, aB3 = 0.f;
            float aB4 = 0.f, aB5 = 0.f, aB6 = 0.f, aB7 = 0.f;
            for (int j = 0; j < mx; j += 4) {   // uniform trip: full exec
                int eA = beglA + j, eB = beglB + j;
                int sA0 = __shfl(svA, min(eA, 63));       // shfl ALWAYS full exec
                int sA1 = __shfl(svA, min(eA + 1, 63));
                int sA2 = __shfl(svA, min(eA + 2, 63));
                int sA3 = __shfl(svA, min(eA + 3, 63));
                int sB0 = __shfl(svB, min(eB, 63));
                int sB1 = __shfl(svB, min(eB + 1, 63));
                int sB2 = __shfl(svB, min(eB + 2, 63));
                int sB3 = __shfl(svB, min(eB + 3, 63));
                if (eA + 3 >= 64) {              // rare: degree > 64
                    sA0 = ssrc[min(b0A + eA, EE - 1)];
                    sA1 = ssrc[min(b0A + eA + 1, EE - 1)];
                    sA2 = ssrc[min(b0A + eA + 2, EE - 1)];
                    sA3 = ssrc[min(b0A + eA + 3, EE - 1)];
                }
                if (eB + 3 >= 64) {
                    sB0 = ssrc[min(b0B + eB, EE - 1)];
                    sB1 = ssrc[min(b0B + eB + 1, EE - 1)];
                    sB2 = ssrc[min(b0B + eB + 2, EE - 1)];
                    sB3 = ssrc[min(b0B + eB + 3, EE - 1)];
                }
                uint4 uA0 = h16[(size_t)sA0 * 16 + ll];   // 8 loads in flight
                uint4 uA1 = h16[(size_t)sA1 * 16 + ll];
                uint4 uA2 = h16[(size_t)sA2 * 16 + ll];
                uint4 uA3 = h16[(size_t)sA3 * 16 + ll];
                uint4 uB0 = h16[(size_t)sB0 * 16 + ll];
                uint4 uB1 = h16[(size_t)sB1 * 16 + ll];
                uint4 uB2 = h16[(size_t)sB2 * 16 + ll];
                uint4 uB3 = h16[(size_t)sB3 * 16 + ll];
                if (j < lenA) {
                    aA0 += bflo(uA0.x); aA1 += bfhi(uA0.x);
                    aA2 += bflo(uA0.y); aA3 += bfhi(uA0.y);
                    aA4 += bflo(uA0.z); aA5 += bfhi(uA0.z);
                    aA6 += bflo(uA0.w); aA7 += bfhi(uA0.w);
                }
                if (j + 1 < lenA) {
                    aA0 += bflo(uA1.x); aA1 += bfhi(uA1.x);
                    aA2 += bflo(uA1.y); aA3 += bfhi(uA1.y);
                    aA4 += bflo(uA1.z); aA5 += bfhi(uA1.z);
                    aA6 += bflo(uA1.w); aA7 += bfhi(uA1.w);
                }
                if (j + 2 < lenA) {
                    aA0 += bflo(uA2.x); aA1 += bfhi(uA2.x);
                    aA2 += bflo(uA2.y); aA3 += bfhi(uA2.y);
                    aA4 += bflo(uA2.z); aA5 += bfhi(uA2.z);
                    aA6 += bflo(uA2.w); aA7 += bfhi(uA2.w);
                }
                if (j + 3 < lenA) {
                    aA0 += bflo(uA3.x); aA1 += bfhi(uA3.x);
                    aA2 += bflo(uA3.y); aA3 += bfhi(uA3.y);
                    aA4 += bflo(uA3.z); aA5 += bfhi(uA3.z);
                    aA6 += bflo(uA3.w); aA7 += bfhi(uA3.w);
                }
                if (j < lenB) {
                    aB0 += bflo(uB0.x); aB1 += bfhi(uB0.x);
                    aB2 += bflo(uB0.y); aB3 += bfhi(uB0.y);
                    aB4 += bflo(uB0.z); aB5 += bfhi(uB0.z);
                    aB6 += bflo(uB0.w); aB7 += bfhi(uB0.w);
                }
                if (j + 1 < lenB) {
                    aB0 += bflo(uB1.x); aB1 += bfhi(uB1.x);
                    aB2 += bflo(uB1.y); aB3 += bfhi(uB1.y);
                    aB4 += bflo(uB1.z); aB5 += bfhi(uB1.z);
                    aB6 += bflo(uB1.w); aB7 += bfhi(uB1.w);
                }
                if (j + 2 < lenB) {
                    aB0 += bflo(uB2.x); aB1 += bfhi(uB2.x);
                    aB2 += bflo(uB2.y); aB3 += bfhi(uB2.y);
                    aB4 += bflo(uB2.z); aB5 += bfhi(uB2.z);
                    aB6 += bflo(uB2.w); aB7 += bfhi(uB2.w);
                }
                if (j + 3 < lenB) {
                    aB0 += bflo(uB3.x); aB1 += bfhi(uB3.x);
                    aB2 += bflo(uB3.y); aB3 += bfhi(uB3.y);
                    aB4 += bflo(uB3.z); aB5 += bfhi(uB3.z);
                    aB6 += bflo(uB3.w); aB7 += bfhi(uB3.w);
                }
            }
            float invA = 1.0f / (float)max(lenA, 1);
            float invB = 1.0f / (float)max(lenB, 1);
            uint4 oA, oB;
            oA.x = f2bf(aA0 * invA) | (f2bf(aA1 * invA) << 16);
            oA.y = f2bf(aA2 * invA) | (f2bf(aA3 * invA) << 16);
            oA.z = f2bf(aA4 * invA) | (f2bf(aA5 * invA) << 16);
            oA.w = f2bf(aA6 * invA) | (f2bf(aA7 * invA) << 16);
            oB.x = f2bf(aB0 * invB) | (f2bf(aB1 * invB) << 16);
            oB.y = f2bf(aB2 * invB) | (f2bf(aB3 * invB) << 16);
            oB.z = f2bf(aB4 * invB) | (f2bf(aB5 * invB) << 16);
            oB.w = f2bf(aB6 * invB) | (f2bf(aB7 * invB) << 16);
            *(uint4*)(&As[nlA * LDW + (r * 16 + ll) * 8]) = oA;
            *(uint4*)(&As[nlB * LDW + (r * 16 + ll) * 8]) = oB;
        }
    }
    // ---- root rows: cols [1024,1152) = chunks [128,144); 512 thr x 16B = 32 rows
    {
        int row = tid >> 4;                  // 0..31
        int cc = tid & 15;
        uint4 v = h16[(size_t)min(nbase + row, NN - 1) * 16 + cc];
        *(uint4*)(&As[row * LDW + (128 + cc) * 8]) = v;
    }
    __syncthreads();
    // ---- phase 2: MFMA. O=128 -> wave w: col-tile w, m-subtiles 0,1;
    //      O=64 -> wave w: col-tile w&3, m-subtile w>>2.
    constexpr int NTILE = O / 16;
    const int cw = w % NTILE;
    const int mt0 = (NTILE == 8) ? 0 : (w / NTILE);
    constexpr int NMT = (NTILE == 8) ? 2 : 1;
    const int lr = lane & 15, hi = lane >> 4;
    f32x4 acc[NMT] = {};
    const ushort* wcol = WT + (size_t)(cw * 16 + lr) * KTOT + hi * 8;
#pragma unroll
    for (int ks = 0; ks < 36; ++ks) {
        bf16x8 bb = *(const bf16x8*)(wcol + ks * 32);
        int g = ks * 4 + hi;
#pragma unroll
        for (int m = 0; m < NMT; ++m) {
            int row = (mt0 + m) * 16 + lr;
            bf16x8 a = *(const bf16x8*)(&As[row * LDW + g * 8]);
            acc[m] = __builtin_amdgcn_mfma_f32_16x16x32_bf16(a, bb, acc[m], 0, 0, 0);
        }
    }
    int col = cw * 16 + lr;
    float bs = bias[col];
#pragma unroll
    for (int m = 0; m < NMT; ++m) {
#pragma unroll
        for (int j = 0; j < 4; ++j) {        // C/D: col=lane&15, row=(lane>>4)*4+j
            int row = nbase + (mt0 + m) * 16 + hi * 4 + j;
            if (row >= NN) continue;
            float v = acc[m][j] + bs;
            if (RELU) v = fmaxf(v, 0.f);
            if (OUTF32) ((float*)outv)[(size_t)row * O + col] = v;
            else ((ushort*)outv)[(size_t)row * O + col] = (ushort)f2bf(v);
        }
    }
}

// ---------------- final log_softmax over 64 cols ----------------
__global__ void k_logsoftmax(const float* __restrict__ in, float* __restrict__ out) {
    int row = blockIdx.x * 4 + (threadIdx.x >> 6);
    int lane = threadIdx.x & 63;
    if (row >= NN) return;
    float v = in[(size_t)row * 64 + lane];
    float m = v;
#pragma unroll
    for (int off = 32; off; off >>= 1) m = fmaxf(m, __shfl_xor(m, off, 64));
    float e = expf(v - m);
    float s = e;
#pragma unroll
    for (int off = 32; off; off >>= 1) s += __shfl_xor(s, off, 64);
    out[(size_t)row * 64 + lane] = v - m - logf(s);
}

extern "C" void kernel_launch(void* const* d_in, const int* in_sizes, int n_in,
                              void* d_out, int out_size, void* d_ws, size_t ws_size,
                              hipStream_t stream) {
    const float* x  = (const float*)d_in[0];
    const int*   ei = (const int*)d_in[1];
    const int*   et = (const int*)d_in[2];
    const float* W[4]    = {(const float*)d_in[3], (const float*)d_in[6],
                            (const float*)d_in[9], (const float*)d_in[12]};
    const float* root[4] = {(const float*)d_in[4], (const float*)d_in[7],
                            (const float*)d_in[10], (const float*)d_in[13]};
    const float* bias[4] = {(const float*)d_in[5], (const float*)d_in[8],
                            (const float*)d_in[11], (const float*)d_in[14]};

    if (ws_size < WS_NEED) return;

    char* ws = (char*)d_ws;
    ushort* hb0  = (ushort*)(ws + OFF_HB0);
    ushort* hb1  = (ushort*)(ws + OFF_HB1);
    ushort* xb   = (ushort*)(ws + OFF_XB);
    float*  lg   = (float*)(ws + OFF_LG);
    ushort* WT   = (ushort*)(ws + OFF_WT);
    int*   offs  = (int*)(ws + OFF_OFFS);
    int*   cur   = (int*)(ws + OFF_CUR);
    int*   ssrc  = (int*)(ws + OFF_SRT);
    int*   bsums = (int*)(ws + OFF_BS);
    ushort* WTl[4] = {WT, WT + 147456, WT + 2 * 147456, WT + 3 * 147456};

    // one-time converts
    k_cvt<<<(NN * 32 + 255) / 256, 256, 0, stream>>>(x, xb);
    k_wt<<<128, 256, 0, stream>>>(W[0], root[0], WTl[0], 128);
    k_wt<<<128, 256, 0, stream>>>(W[1], root[1], WTl[1], 128);
    k_wt<<<128, 256, 0, stream>>>(W[2], root[2], WTl[2], 128);
    k_wt<<<64,  256, 0, stream>>>(W[3], root[3], WTl[3], 64);

    // edge sort by segment key s = dst*8 + etype
    hipMemsetAsync(cur, 0, RN * sizeof(int), stream);
    k_hist<<<(EE + 255) / 256, 256, 0, stream>>>(ei, et, cur);
    k_scan1<<<NBLK, 1024, 0, stream>>>(cur, offs, bsums);
    k_scan2<<<1, 1024, 0, stream>>>(bsums);
    k_scan3<<<NBLK, 1024, 0, stream>>>(offs, bsums);
    hipMemsetAsync(cur, 0, RN * sizeof(int), stream);
    k_scatter<<<(EE + 255) / 256, 256, 0, stream>>>(ei, et, offs, cur, ssrc);

    const int G = (NN + 31) / 32;   // 1563
    k_fused<128, true,  false><<<G, 512, 0, stream>>>(xb,  offs, ssrc, WTl[0], bias[0], hb0);
    k_fused<128, true,  false><<<G, 512, 0, stream>>>(hb0, offs, ssrc, WTl[1], bias[1], hb1);
    k_fused<128, true,  false><<<G, 512, 0, stream>>>(hb1, offs, ssrc, WTl[2], bias[2], hb0);
    k_fused<64,  false, true ><<<G, 512, 0, stream>>>(hb0, offs, ssrc, WTl[3], bias[3], lg);
    k_logsoftmax<<<(NN + 3) / 4, 256, 0, stream>>>(lg, (float*)d_out);
}